// Round 1
// baseline (32.738 us; speedup 1.0000x reference)
//
#include <hip/hip_runtime.h>
#include <math.h>

#define B_ 8
#define U_ 512
#define T_ 1024
#define H_ 512
#define D_ 128
#define K_ 10

#define UT 16     // u rows per block (kernel 3)
#define TC 64     // t chunk size

// ---------------- Kernel 1: p = exp(h_t @ W + b) -----------------
// One wave (64 threads) per (b,u) row; lane j < 30 computes output col j.
__global__ __launch_bounds__(64)
void params_kernel(const float* __restrict__ h_t,
                   const float* __restrict__ W,
                   const float* __restrict__ bias,
                   float* __restrict__ alpha,
                   float* __restrict__ beta,
                   float* __restrict__ kinc) {
    int row = blockIdx.x;            // 0..B*U-1
    int j = threadIdx.x;             // 0..63
    if (j >= 3 * K_) return;
    const float* h = h_t + (size_t)row * H_;
    float a0 = 0.f, a1 = 0.f, a2 = 0.f, a3 = 0.f;
    for (int hh = 0; hh < H_; hh += 4) {
        float h0 = h[hh], h1 = h[hh + 1], h2 = h[hh + 2], h3 = h[hh + 3];
        a0 += h0 * W[(hh + 0) * 3 * K_ + j];
        a1 += h1 * W[(hh + 1) * 3 * K_ + j];
        a2 += h2 * W[(hh + 2) * 3 * K_ + j];
        a3 += h3 * W[(hh + 3) * 3 * K_ + j];
    }
    float p = __expf((a0 + a1) + (a2 + a3) + bias[j]);
    int k = j % K_;
    int which = j / K_;
    size_t idx = (size_t)row * K_ + k;
    if (which == 0)      alpha[idx] = p;
    else if (which == 1) beta[idx]  = p;
    else                 kinc[idx]  = 0.2f * p;
}

// ---------------- Kernel 2: kappa = cumsum(kinc, axis=u), in place ----------
// One wave per (b,k): lane l owns u = l*8 .. l*8+7.
__global__ __launch_bounds__(64)
void scan_kernel(float* __restrict__ kinc) {
    int b = blockIdx.x / K_;
    int k = blockIdx.x % K_;
    int lane = threadIdx.x;          // 0..63
    int ubase = lane * 8;
    float v[8];
    float run = 0.f;
    for (int i = 0; i < 8; ++i) {
        float x = kinc[((size_t)(b * U_) + ubase + i) * K_ + k];
        run += x;
        v[i] = run;                  // inclusive within lane
    }
    float tot = run;
    float x = tot;
    for (int d = 1; d < 64; d <<= 1) {
        float y = __shfl_up(x, d, 64);
        if (lane >= d) x += y;
    }
    float excl = x - tot;            // exclusive prefix of lane totals
    for (int i = 0; i < 8; ++i)
        kinc[((size_t)(b * U_) + ubase + i) * K_ + k] = v[i] + excl;
}

// ---------------- Kernel 3: phi + masked matmul -----------------
// Block = 256 threads handles (b, 16 u-rows). Skips t-chunks where all
// Gaussian terms underflow to 0 in f32 (beta*(kappa-t)^2 > 88).
__global__ __launch_bounds__(256)
void attend_kernel(const float* __restrict__ alpha,
                   const float* __restrict__ beta,
                   const float* __restrict__ kappa,
                   const float* __restrict__ ctx,
                   const float* __restrict__ mask,
                   float* __restrict__ out) {
    __shared__ float a_s[UT][K_], b_s[UT][K_], k_s[UT][K_];
    __shared__ float phi_s[UT][TC + 1];       // +1 pad: phase-B reads hit distinct banks
    __shared__ float ctx_s[TC][D_];           // 32 KB
    __shared__ float red_lo[256], red_hi[256];

    int tid = threadIdx.x;
    int b = blockIdx.y;
    int u0 = blockIdx.x * UT;

    // load per-u params, compute active-t bounds
    float lo = 1e30f, hi = -1e30f;
    if (tid < UT * K_) {
        int u_l = tid / K_, k = tid % K_;
        size_t idx = ((size_t)(b * U_) + u0 + u_l) * K_ + k;
        float av = alpha[idx], bv = beta[idx], kv = kappa[idx];
        a_s[u_l][k] = av; b_s[u_l][k] = bv; k_s[u_l][k] = kv;
        float r = sqrtf(88.f / bv);
        lo = kv - r; hi = kv + r;
    }
    red_lo[tid] = lo; red_hi[tid] = hi;
    __syncthreads();
    for (int s = 128; s > 0; s >>= 1) {
        if (tid < s) {
            red_lo[tid] = fminf(red_lo[tid], red_lo[tid + s]);
            red_hi[tid] = fmaxf(red_hi[tid], red_hi[tid + s]);
        }
        __syncthreads();
    }
    float tile_lo = red_lo[0], tile_hi = red_hi[0];
    int t_begin = max(0, (int)floorf(tile_lo));
    int t_end   = min(T_, (int)ceilf(tile_hi) + 1);
    t_begin = (t_begin / TC) * TC;

    // thread -> (u row, d columns {4g..4g+3} U {64+4g..64+4g+3})
    int u_l = tid >> 4;   // 0..15
    int g   = tid & 15;   // 0..15
    float acc[8];
    #pragma unroll
    for (int i = 0; i < 8; ++i) acc[i] = 0.f;

    for (int t0 = t_begin; t0 < t_end; t0 += TC) {
        __syncthreads();  // protect phi_s/ctx_s from previous iteration's readers
        // stage ctx chunk (coalesced float4)
        {
            const float4* src = (const float4*)(ctx + (((size_t)b * T_ + t0) * D_));
            float4* dst = (float4*)(&ctx_s[0][0]);
            #pragma unroll
            for (int i = 0; i < (TC * D_ / 4) / 256; ++i)
                dst[tid + 256 * i] = src[tid + 256 * i];
        }
        // phi for this chunk: 16x64 values, 4 per thread
        #pragma unroll
        for (int i = 0; i < 4; ++i) {
            int lin = tid + 256 * i;
            int uu = lin >> 6;        // whole wave shares uu -> broadcast param reads
            int tl = lin & 63;
            float tf = (float)(t0 + tl);
            float ph = 0.f;
            #pragma unroll
            for (int k = 0; k < K_; ++k) {
                float d = k_s[uu][k] - tf;
                float x = b_s[uu][k] * d * d;
                ph += a_s[uu][k] * __expf(-x);
            }
            phi_s[uu][tl] = ph * mask[(size_t)b * T_ + t0 + tl];
        }
        __syncthreads();
        // matmul: acc += phi * ctx
        for (int tl = 0; tl < TC; ++tl) {
            float ph = phi_s[u_l][tl];
            const float4* c = (const float4*)(&ctx_s[tl][0]);
            float4 c0 = c[g];         // d = 4g..4g+3
            float4 c1 = c[g + 16];    // d = 64+4g..64+4g+3
            acc[0] += ph * c0.x; acc[1] += ph * c0.y;
            acc[2] += ph * c0.z; acc[3] += ph * c0.w;
            acc[4] += ph * c1.x; acc[5] += ph * c1.y;
            acc[6] += ph * c1.z; acc[7] += ph * c1.w;
        }
    }

    // write out (every element written every launch, even if all-zero)
    float* orow = out + ((size_t)b * U_ + u0 + u_l) * D_;
    *(float4*)(orow + 4 * g)      = make_float4(acc[0], acc[1], acc[2], acc[3]);
    *(float4*)(orow + 64 + 4 * g) = make_float4(acc[4], acc[5], acc[6], acc[7]);
}

extern "C" void kernel_launch(void* const* d_in, const int* in_sizes, int n_in,
                              void* d_out, int out_size, void* d_ws, size_t ws_size,
                              hipStream_t stream) {
    const float* h_t  = (const float*)d_in[0];
    const float* ctx  = (const float*)d_in[1];
    const float* mask = (const float*)d_in[2];
    const float* W    = (const float*)d_in[3];
    const float* bias = (const float*)d_in[4];
    float* out = (float*)d_out;

    const size_t NPARAM = (size_t)B_ * U_ * K_;   // 40960 floats
    float* alpha = (float*)d_ws;
    float* beta  = alpha + NPARAM;
    float* kinc  = beta + NPARAM;                 // becomes kappa after scan

    params_kernel<<<dim3(B_ * U_), dim3(64), 0, stream>>>(h_t, W, bias, alpha, beta, kinc);
    scan_kernel<<<dim3(B_ * K_), dim3(64), 0, stream>>>(kinc);
    attend_kernel<<<dim3(U_ / UT, B_), dim3(256), 0, stream>>>(alpha, beta, kinc, ctx, mask, out);
}